// Round 11
// baseline (190.576 us; speedup 1.0000x reference)
//
#include <hip/hip_runtime.h>
#include <hip/hip_bf16.h>
#include <math.h>

// Problem constants
constexpr int kB     = 4;
constexpr int kH     = 48;
constexpr int kW     = 48;
constexpr int kHW    = 2304;   // 48*48
constexpr int kC     = 256;
constexpr int kHeads = 8;
constexpr int kHD    = 32;
constexpr float kScale = 0.17677669529663687f;  // 32^-0.5

typedef __bf16 bf16x8 __attribute__((ext_vector_type(8)));
typedef float  f32x4  __attribute__((ext_vector_type(4)));
typedef unsigned int   uint32x4 __attribute__((ext_vector_type(4)));
typedef unsigned short ushort8v __attribute__((ext_vector_type(8)));

static __device__ __forceinline__ unsigned short f2bf_bits(float f) {
    return __builtin_bit_cast(unsigned short, __float2bfloat16(f));
}

// packed f32x2 -> bf16x2 in one instruction
static __device__ __forceinline__ unsigned cvt_pk_bf16(float lo, float hi) {
    unsigned r;
    asm("v_cvt_pk_bf16_f32 %0, %1, %2" : "=v"(r) : "v"(lo), "v"(hi));
    return r;
}

// VALU cross-lane swaps (gfx950)
static __device__ __forceinline__ void permlane16_swap(unsigned& a, unsigned& b) {
    asm("v_permlane16_swap_b32 %0, %1" : "+v"(a), "+v"(b));
}
static __device__ __forceinline__ void permlane32_swap(unsigned& a, unsigned& b) {
    asm("v_permlane32_swap_b32 %0, %1" : "+v"(a), "+v"(b));
}

// async global->LDS, 16B per lane; LDS dest = wave-uniform base + lane*16
static __device__ __forceinline__ void gll16(const void* g, void* l) {
    __builtin_amdgcn_global_load_lds(
        (const __attribute__((address_space(1))) void*)g,
        (__attribute__((address_space(3))) void*)l, 16, 0, 0);
}

// ---------------------------------------------------------------------------
// Kernel 0: prep — cast x to bf16 + transpose Wq/Wk/Wv/Wo to bf16 Wt[n][k].
// ---------------------------------------------------------------------------
__global__ __launch_bounds__(256) void prep_kernel(
    const float* __restrict__ x,
    const float* __restrict__ Wq, const float* __restrict__ Wk,
    const float* __restrict__ Wv, const float* __restrict__ Wo,
    unsigned short* __restrict__ xb, unsigned short* __restrict__ wt)
{
    const int bid = blockIdx.x;
    if (bid < 2304) {
        const int i = (bid * 256 + threadIdx.x) * 4;
        const float4 v = *reinterpret_cast<const float4*>(x + i);
        alignas(8) unsigned short u[4] = {f2bf_bits(v.x), f2bf_bits(v.y),
                                          f2bf_bits(v.z), f2bf_bits(v.w)};
        *reinterpret_cast<unsigned long long*>(xb + i) =
            *reinterpret_cast<unsigned long long*>(u);
    } else {
        const int e = (bid - 2304) * 256 + threadIdx.x;
        const int m = e >> 16;
        const int r = e & 65535;
        const int k = r >> 8;
        const int n = r & 255;
        const float* W = (m == 0) ? Wq : ((m == 1) ? Wk : ((m == 2) ? Wv : Wo));
        wt[(size_t)m * 65536 + n * 256 + k] = f2bf_bits(W[k * 256 + n]);
    }
}

// ---------------------------------------------------------------------------
// Kernel 1: QKV projection via bf16 MFMA (fused bias/scale/RoPE; z=2 emits
// vt bf16 [bh][d][hw] + vb fp32).
// ---------------------------------------------------------------------------
__global__ __launch_bounds__(256) void qkv_mfma_kernel(
    const unsigned short* __restrict__ xb, const unsigned short* __restrict__ wt,
    const float* __restrict__ bq, const float* __restrict__ bk,
    const float* __restrict__ bv,
    const float* __restrict__ sinb, const float* __restrict__ cosb,
    unsigned short* __restrict__ qbh, unsigned short* __restrict__ kbh,
    unsigned short* __restrict__ vt, float* __restrict__ vb)
{
    const int z = blockIdx.z;
    const unsigned short* wz = wt + (size_t)z * 65536;
    const float* bt = (z == 0) ? bq : ((z == 1) ? bk : bv);
    const int tid  = threadIdx.x;
    const int w    = tid >> 6;
    const int lane = tid & 63;
    const int l    = lane & 15;
    const int g    = lane >> 4;
    const int m0   = blockIdx.x * 64 + w * 16;
    const int nb   = blockIdx.y * 64;

    f32x4 acc[4] = {};
    const unsigned short* xrow = xb + (size_t)(m0 + l) * 256;
    #pragma unroll
    for (int kc = 0; kc < 8; ++kc) {
        const bf16x8 a = *reinterpret_cast<const bf16x8*>(xrow + kc * 32 + g * 8);
        #pragma unroll
        for (int j = 0; j < 4; ++j) {
            const bf16x8 b = *reinterpret_cast<const bf16x8*>(
                wz + (size_t)(nb + 16 * j + l) * 256 + kc * 32 + g * 8);
            acc[j] = __builtin_amdgcn_mfma_f32_16x16x32_bf16(a, b, acc[j], 0, 0, 0);
        }
    }

    int tok[4], bidx[4], hw[4];
    #pragma unroll
    for (int r = 0; r < 4; ++r) {
        tok[r]  = m0 + 4 * g + r;
        bidx[r] = tok[r] / kHW;
        hw[r]   = tok[r] - bidx[r] * kHW;
    }
    const float scl = (z == 1) ? kScale : 1.0f;

    if (z == 2) {
        #pragma unroll
        for (int j = 0; j < 4; ++j) {
            const int c = nb + 16 * j + l;
            const int head = c >> 5, d = c & 31;
            const float bias = bt[c];
            float t[4];
            #pragma unroll
            for (int r = 0; r < 4; ++r) t[r] = acc[j][r] + bias;
            #pragma unroll
            for (int r = 0; r < 4; ++r)
                vb[(((size_t)(bidx[r] * kHeads + head) * kHW + hw[r]) << 5) + d] = t[r];
            alignas(8) unsigned short u[4] = {f2bf_bits(t[0]), f2bf_bits(t[1]),
                                              f2bf_bits(t[2]), f2bf_bits(t[3])};
            *reinterpret_cast<unsigned long long*>(
                vt + ((size_t)(bidx[0] * kHeads + head) * kHD + d) * kHW + hw[0]) =
                *reinterpret_cast<unsigned long long*>(u);
        }
    } else {
        unsigned short* ob = (z == 0) ? qbh : kbh;
        #pragma unroll
        for (int j = 0; j < 4; ++j) {
            const int c = nb + 16 * j + l;
            const int head = c >> 5, d = c & 31;
            const float bias = bt[c];
            float t[4];
            #pragma unroll
            for (int r = 0; r < 4; ++r) t[r] = (acc[j][r] + bias) * scl;
            #pragma unroll
            for (int r = 0; r < 4; ++r) {
                const float p = __shfl_xor(t[r], 1);
                const float cs = cosb[hw[r] * 32 + d];
                const float sn = sinb[hw[r] * 32 + d];
                const float o = (d & 1) ? (t[r] * cs + p * sn)
                                        : (t[r] * cs - p * sn);
                ob[(((size_t)(bidx[r] * kHeads + head) * kHW + hw[r]) << 5) + d] =
                    f2bf_bits(o);
            }
        }
    }
}

// ---------------------------------------------------------------------------
// Kernel 3: LePE 5x5 depthwise conv on v (head-major in, token-major out)
// ---------------------------------------------------------------------------
__global__ __launch_bounds__(256) void lepe_kernel(
    const float* __restrict__ vb,
    const float* __restrict__ lw, const float* __restrict__ lb,
    float* __restrict__ lepe)
{
    const int c   = threadIdx.x;
    const int bhw = blockIdx.x;
    const int b   = bhw / kHW;
    const int hw  = bhw % kHW;
    const int h   = hw / kW;
    const int w   = hw % kW;
    const int head = c >> 5;
    const int d    = c & 31;

    const float* vsrc = vb + ((size_t)(b * kHeads + head) * kHW) * kHD + d;
    float acc = lb[c];
    #pragma unroll
    for (int dh = 0; dh < 5; ++dh) {
        const int h2 = h + dh - 2;
        if (h2 < 0 || h2 >= kH) continue;
        #pragma unroll
        for (int dw = 0; dw < 5; ++dw) {
            const int w2 = w + dw - 2;
            if (w2 < 0 || w2 >= kW) continue;
            acc += vsrc[(size_t)(h2 * kW + w2) * kHD] * lw[(dh * 5 + dw) * kC + c];
        }
    }
    lepe[(size_t)bhw * kC + c] = acc;
}

// ---------------------------------------------------------------------------
// Kernel 4: MFMA attention, KVBLK=32 -> 40KB LDS -> 4 blocks/CU (8 waves/SIMD).
// 512 threads = 8 waves: wave w = (batch b=w&3, q-sub-tile sh=w>>2).
// Staging roles: w0-3 = 1 mask gll + 2 K glls (vmcnt 3); w4-7 = 2 V glls
// (vmcnt 2). Counted dbuf, setprio around the MFMA/softmax core, pure-VALU
// P redistribution (permlane swaps).
// ---------------------------------------------------------------------------
__global__ __launch_bounds__(512, 8) void attn_mfma_kernel(
    const __hip_bfloat16* __restrict__ qb, const __hip_bfloat16* __restrict__ kb,
    const __hip_bfloat16* __restrict__ vt, const float* __restrict__ mask,
    float* __restrict__ po, float* __restrict__ ls, int kspan)
{
    extern __shared__ __align__(16) char smem[];   // 2 x (4K mask + 8K K + 8K V)
    constexpr int kBufStride = 20480;
    constexpr int kKOff = 4096;
    constexpr int kVOff = 12288;

    const int head = blockIdx.y;
    const int ksl  = blockIdx.z;
    const int tid  = threadIdx.x;
    const int w    = tid >> 6;          // 0..7
    const int b    = w & 3;             // batch
    const int sh   = w >> 2;            // this wave's q-sub-tile (0 or 1)
    const int bh   = b * kHeads + head;
    const int lane = tid & 63;
    const int lq   = lane & 15;
    const int g    = lane >> 4;
    const int q0   = blockIdx.x * 32;
    const int kt0  = ksl * kspan;
    const int nt   = kspan >> 5;        // 32-key tiles
    const bool odd16 = (g & 1);

    // Q B-fragment for this wave's sub-tile
    const bf16x8 qfrag = *reinterpret_cast<const bf16x8*>(
        reinterpret_cast<const unsigned short*>(qb) +
        ((size_t)bh * kHW + q0 + 16 * sh + lq) * kHD + g * 8);

    // staging sources (pre-swizzled; LDS written linearly)
    const float* msrc = nullptr;
    const unsigned short* kvsrc[2];
    {
        const unsigned short* kb_bh =
            reinterpret_cast<const unsigned short*>(kb) + (size_t)bh * kHW * kHD;
        const unsigned short* vt_bh =
            reinterpret_cast<const unsigned short*>(vt) + (size_t)bh * kHD * kHW;
        if (sh == 0) {   // waves 0..3: mask row-block w + K for batch b
            const int mrow = w * 8 + (lane >> 3);
            const int mslot = (lane & 7) ^ (mrow & 7);
            msrc = mask + ((size_t)head * kHW + q0 + mrow) * kHW + kt0 + mslot * 4;
            #pragma unroll
            for (int i = 0; i < 2; ++i) {
                const int key   = i * 16 + (lane >> 2);
                const int kslot = (lane & 3) ^ (key & 3);
                kvsrc[i] = kb_bh + (size_t)(kt0 + key) * kHD + kslot * 8;
            }
        } else {         // waves 4..7: V for batch b
            #pragma unroll
            for (int i = 0; i < 2; ++i) {
                const int d    = i * 16 + (lane >> 2);
                const int vslot = (lane & 3) ^ (d & 3);
                kvsrc[i] = vt_bh + (size_t)d * kHW + kt0 + vslot * 8;
            }
        }
    }

    auto STAGE = [&](int bufo, int tt) {
        if (sh == 0) {
            gll16(msrc + (size_t)tt * 32, smem + bufo + w * 1024);
            #pragma unroll
            for (int i = 0; i < 2; ++i)
                gll16(kvsrc[i] + (size_t)tt * 1024,
                      smem + bufo + kKOff + b * 2048 + i * 1024);
        } else {
            #pragma unroll
            for (int i = 0; i < 2; ++i)
                gll16(kvsrc[i] + (size_t)tt * 32,
                      smem + bufo + kVOff + b * 2048 + i * 1024);
        }
    };

    f32x4 o0 = {0.f, 0.f, 0.f, 0.f};
    f32x4 o1 = {0.f, 0.f, 0.f, 0.f};
    float lsum = 0.f;

    // swizzled fragment read offsets
    const int kvx = (g ^ (lq & 3)) * 16;

    STAGE(0, 0);

    int cur = 0;
    for (int t = 0; t < nt; ++t) {
        if (t + 1 < nt) {
            STAGE(cur ^ kBufStride, t + 1);
            if (sh == 0) asm volatile("s_waitcnt vmcnt(3)" ::: "memory");
            else         asm volatile("s_waitcnt vmcnt(2)" ::: "memory");
        } else {
            asm volatile("s_waitcnt vmcnt(0)" ::: "memory");
        }
        __builtin_amdgcn_s_barrier();
        __builtin_amdgcn_sched_barrier(0);

        const char* mb  = smem + cur;
        const char* kbf = smem + cur + kKOff + b * 2048;
        const char* vbf = smem + cur + kVOff + b * 2048;

        bf16x8 kf[2];
        #pragma unroll
        for (int j = 0; j < 2; ++j)
            kf[j] = *reinterpret_cast<const bf16x8*>(kbf + (16 * j + lq) * 64 + kvx);
        const bf16x8 va = *reinterpret_cast<const bf16x8*>(vbf + lq * 64 + kvx);
        const bf16x8 vc = *reinterpret_cast<const bf16x8*>(vbf + (16 + lq) * 64 + kvx);

        __builtin_amdgcn_s_setprio(1);
        f32x4 st[2];
        #pragma unroll
        for (int j = 0; j < 2; ++j) {
            const f32x4 mc = *reinterpret_cast<const f32x4*>(
                mb + (16 * sh + lq) * 128 + (((4 * j + g) ^ (lq & 7)) * 16));
            st[j] = __builtin_amdgcn_mfma_f32_16x16x32_bf16(kf[j], qfrag, mc, 0, 0, 0);
        }

        unsigned p32[2][2];
        #pragma unroll
        for (int j = 0; j < 2; ++j) {
            const float e0 = __expf(st[j][0]);
            const float e1 = __expf(st[j][1]);
            const float e2 = __expf(st[j][2]);
            const float e3 = __expf(st[j][3]);
            lsum += (e0 + e1) + (e2 + e3);
            p32[j][0] = cvt_pk_bf16(e0, e1);
            p32[j][1] = cvt_pk_bf16(e2, e3);
        }

        // P redistribution (S^T lane layout -> PV A-fragment), pure VALU
        unsigned sj[2][2][2];
        #pragma unroll
        for (int j = 0; j < 2; ++j)
            #pragma unroll
            for (int r = 0; r < 2; ++r) {
                unsigned a = p32[j][r], b2 = p32[j][r];
                permlane16_swap(a, b2);
                sj[j][r][0] = a; sj[j][r][1] = b2;
            }
        unsigned pw0[4];
        #pragma unroll
        for (int w2 = 0; w2 < 4; ++w2) {
            const int r = w2 & 1, c = w2 >> 1;
            unsigned pa = sj[0][r][c], pb = sj[1][r][c];
            permlane32_swap(pa, pb);
            pw0[w2] = odd16 ? pb : pa;
        }
        uint32x4 w0v = {pw0[0], pw0[1], pw0[2], pw0[3]};
        const bf16x8 pa0 = __builtin_bit_cast(bf16x8, w0v);

        o0 = __builtin_amdgcn_mfma_f32_16x16x32_bf16(pa0, va, o0, 0, 0, 0);
        o1 = __builtin_amdgcn_mfma_f32_16x16x32_bf16(pa0, vc, o1, 0, 0, 0);
        __builtin_amdgcn_s_setprio(0);

        asm volatile("s_waitcnt lgkmcnt(0)" ::: "memory");
        __builtin_amdgcn_s_barrier();
        cur ^= kBufStride;
    }

    // row-sum (partial over this k-range) + un-normalized partial writes
    lsum += __shfl_xor(lsum, 16);
    lsum += __shfl_xor(lsum, 32);

    const size_t pbase = ((size_t)ksl * (kB * kHeads) + bh) * kHW;
    #pragma unroll
    for (int r = 0; r < 4; ++r) {
        float* orow = po + (pbase + q0 + 16 * sh + 4 * g + r) * kHD + lq;
        orow[0]  = o0[r];
        orow[16] = o1[r];
    }
    if (lane < 16) ls[pbase + q0 + 16 * sh + lq] = lsum;
}

// ---------------------------------------------------------------------------
// Kernel 4b: combine k-split partials + lepe add -> bf16 A matrix for out proj
// ---------------------------------------------------------------------------
__global__ __launch_bounds__(256) void combine_kernel(
    const float* __restrict__ po, const float* __restrict__ ls,
    const float* __restrict__ lepe, unsigned short* __restrict__ abh, int ks)
{
    const int idx = blockIdx.x * 256 + threadIdx.x;
    const int c   = idx & 255;
    const int bhw = idx >> 8;
    const int b   = bhw / kHW;
    const int hw  = bhw % kHW;
    const int head = c >> 5;
    const int d    = c & 31;
    const int bh   = b * kHeads + head;

    float o = 0.f, l = 0.f;
    for (int s = 0; s < ks; ++s) {
        const size_t pbase = ((size_t)s * (kB * kHeads) + bh) * kHW + hw;
        o += po[pbase * kHD + d];
        l += ls[pbase];
    }
    abh[(size_t)idx] = f2bf_bits(o / l + lepe[idx]);
}

// ---------------------------------------------------------------------------
// Kernel 5: output projection via bf16 MFMA.
// ---------------------------------------------------------------------------
__global__ __launch_bounds__(256) void out_mfma_kernel(
    const unsigned short* __restrict__ abh, const unsigned short* __restrict__ wt,
    const float* __restrict__ bo, float* __restrict__ out)
{
    const unsigned short* wz = wt + (size_t)3 * 65536;
    const int tid  = threadIdx.x;
    const int w    = tid >> 6;
    const int lane = tid & 63;
    const int l    = lane & 15;
    const int g    = lane >> 4;
    const int m0   = blockIdx.x * 64 + w * 16;
    const int nb   = blockIdx.y * 64;

    f32x4 acc[4] = {};
    const unsigned short* arow = abh + (size_t)(m0 + l) * 256;
    #pragma unroll
    for (int kc = 0; kc < 8; ++kc) {
        const bf16x8 a = *reinterpret_cast<const bf16x8*>(arow + kc * 32 + g * 8);
        #pragma unroll
        for (int j = 0; j < 4; ++j) {
            const bf16x8 b = *reinterpret_cast<const bf16x8*>(
                wz + (size_t)(nb + 16 * j + l) * 256 + kc * 32 + g * 8);
            acc[j] = __builtin_amdgcn_mfma_f32_16x16x32_bf16(a, b, acc[j], 0, 0, 0);
        }
    }

    #pragma unroll
    for (int j = 0; j < 4; ++j) {
        const int c = nb + 16 * j + l;
        const float bias = bo[c];
        #pragma unroll
        for (int r = 0; r < 4; ++r)
            out[(size_t)(m0 + 4 * g + r) * 256 + c] = acc[j][r] + bias;
    }
}

// ---------------------------------------------------------------------------
extern "C" void kernel_launch(void* const* d_in, const int* in_sizes, int n_in,
                              void* d_out, int out_size, void* d_ws, size_t ws_size,
                              hipStream_t stream)
{
    const float* x    = (const float*)d_in[0];
    const float* sinb = (const float*)d_in[1];
    const float* cosb = (const float*)d_in[2];
    const float* mask = (const float*)d_in[3];
    const float* Wq   = (const float*)d_in[4];
    const float* bq   = (const float*)d_in[5];
    const float* Wk   = (const float*)d_in[6];
    const float* bk   = (const float*)d_in[7];
    const float* Wv   = (const float*)d_in[8];
    const float* bv   = (const float*)d_in[9];
    const float* lw   = (const float*)d_in[10];
    const float* lb   = (const float*)d_in[11];
    const float* Wo   = (const float*)d_in[12];
    const float* bo   = (const float*)d_in[13];
    float* out = (float*)d_out;

    const size_t NT = (size_t)kB * kHeads * kHW * kHD;  // 2359296 per tensor
    const size_t fixed = NT * 4 * 2 + NT * 2 * 5 + 4 * 65536 * 2;

    int ks = 2;
    while (ks > 1) {
        const size_t need = fixed + (size_t)ks * (NT * 4 + (size_t)kB * kHeads * kHW * 4);
        if (need <= ws_size) break;
        ks >>= 1;
    }
    const int kspan = kHW / ks;

    char* base = (char*)d_ws;
    float* vb   = (float*)base;                      base += NT * 4;
    float* lepe = (float*)base;                      base += NT * 4;
    unsigned short* xb  = (unsigned short*)base;     base += NT * 2;
    unsigned short* abh = (unsigned short*)base;     base += NT * 2;
    unsigned short* qbh = (unsigned short*)base;     base += NT * 2;
    unsigned short* kbh = (unsigned short*)base;     base += NT * 2;
    unsigned short* vt  = (unsigned short*)base;     base += NT * 2;
    unsigned short* wt  = (unsigned short*)base;     base += (size_t)4 * 65536 * 2;
    float* po = (float*)base;                        base += (size_t)ks * NT * 4;
    float* ls = (float*)base;                        base += (size_t)ks * kB * kHeads * kHW * 4;

    prep_kernel<<<dim3(3328), 256, 0, stream>>>(x, Wq, Wk, Wv, Wo, xb, wt);
    qkv_mfma_kernel<<<dim3(144, 4, 3), 256, 0, stream>>>(
        xb, wt, bq, bk, bv, sinb, cosb, qbh, kbh, vt, vb);
    lepe_kernel<<<dim3(9216), 256, 0, stream>>>(vb, lw, lb, lepe);
    attn_mfma_kernel<<<dim3(72, 8, ks), 512, 40960, stream>>>(
        (const __hip_bfloat16*)qbh, (const __hip_bfloat16*)kbh,
        (const __hip_bfloat16*)vt, mask, po, ls, kspan);
    combine_kernel<<<dim3(9216), 256, 0, stream>>>(po, ls, lepe, abh, ks);
    out_mfma_kernel<<<dim3(144, 4), 256, 0, stream>>>(abh, wt, bo, out);
}

// Round 12
// 190.175 us; speedup vs baseline: 1.0021x; 1.0021x over previous
//
#include <hip/hip_runtime.h>
#include <hip/hip_bf16.h>
#include <math.h>

// Problem constants
constexpr int kB     = 4;
constexpr int kH     = 48;
constexpr int kW     = 48;
constexpr int kHW    = 2304;   // 48*48
constexpr int kC     = 256;
constexpr int kHeads = 8;
constexpr int kHD    = 32;
constexpr float kScale = 0.17677669529663687f;  // 32^-0.5

typedef __bf16 bf16x8 __attribute__((ext_vector_type(8)));
typedef float  f32x4  __attribute__((ext_vector_type(4)));
typedef unsigned int   uint32x4 __attribute__((ext_vector_type(4)));
typedef unsigned short ushort8v __attribute__((ext_vector_type(8)));

static __device__ __forceinline__ unsigned short f2bf_bits(float f) {
    return __builtin_bit_cast(unsigned short, __float2bfloat16(f));
}

// packed f32x2 -> bf16x2 in one instruction
static __device__ __forceinline__ unsigned cvt_pk_bf16(float lo, float hi) {
    unsigned r;
    asm("v_cvt_pk_bf16_f32 %0, %1, %2" : "=v"(r) : "v"(lo), "v"(hi));
    return r;
}

// VALU cross-lane swaps (gfx950)
static __device__ __forceinline__ void permlane16_swap(unsigned& a, unsigned& b) {
    asm("v_permlane16_swap_b32 %0, %1" : "+v"(a), "+v"(b));
}
static __device__ __forceinline__ void permlane32_swap(unsigned& a, unsigned& b) {
    asm("v_permlane32_swap_b32 %0, %1" : "+v"(a), "+v"(b));
}

// async global->LDS, 16B per lane; LDS dest = wave-uniform base + lane*16
static __device__ __forceinline__ void gll16(const void* g, void* l) {
    __builtin_amdgcn_global_load_lds(
        (const __attribute__((address_space(1))) void*)g,
        (__attribute__((address_space(3))) void*)l, 16, 0, 0);
}

// ---------------------------------------------------------------------------
// Kernel 0: prep — cast x to bf16 + transpose Wq/Wk/Wv/Wo to bf16 Wt[n][k].
// ---------------------------------------------------------------------------
__global__ __launch_bounds__(256) void prep_kernel(
    const float* __restrict__ x,
    const float* __restrict__ Wq, const float* __restrict__ Wk,
    const float* __restrict__ Wv, const float* __restrict__ Wo,
    unsigned short* __restrict__ xb, unsigned short* __restrict__ wt)
{
    const int bid = blockIdx.x;
    if (bid < 2304) {
        const int i = (bid * 256 + threadIdx.x) * 4;
        const float4 v = *reinterpret_cast<const float4*>(x + i);
        alignas(8) unsigned short u[4] = {f2bf_bits(v.x), f2bf_bits(v.y),
                                          f2bf_bits(v.z), f2bf_bits(v.w)};
        *reinterpret_cast<unsigned long long*>(xb + i) =
            *reinterpret_cast<unsigned long long*>(u);
    } else {
        const int e = (bid - 2304) * 256 + threadIdx.x;
        const int m = e >> 16;
        const int r = e & 65535;
        const int k = r >> 8;
        const int n = r & 255;
        const float* W = (m == 0) ? Wq : ((m == 1) ? Wk : ((m == 2) ? Wv : Wo));
        wt[(size_t)m * 65536 + n * 256 + k] = f2bf_bits(W[k * 256 + n]);
    }
}

// ---------------------------------------------------------------------------
// Kernel 1: QKV projection via bf16 MFMA (fused bias/scale/RoPE; z=2 emits
// vt bf16 [bh][d][hw] + vb fp32).
// ---------------------------------------------------------------------------
__global__ __launch_bounds__(256) void qkv_mfma_kernel(
    const unsigned short* __restrict__ xb, const unsigned short* __restrict__ wt,
    const float* __restrict__ bq, const float* __restrict__ bk,
    const float* __restrict__ bv,
    const float* __restrict__ sinb, const float* __restrict__ cosb,
    unsigned short* __restrict__ qbh, unsigned short* __restrict__ kbh,
    unsigned short* __restrict__ vt, float* __restrict__ vb)
{
    const int z = blockIdx.z;
    const unsigned short* wz = wt + (size_t)z * 65536;
    const float* bt = (z == 0) ? bq : ((z == 1) ? bk : bv);
    const int tid  = threadIdx.x;
    const int w    = tid >> 6;
    const int lane = tid & 63;
    const int l    = lane & 15;
    const int g    = lane >> 4;
    const int m0   = blockIdx.x * 64 + w * 16;
    const int nb   = blockIdx.y * 64;

    f32x4 acc[4] = {};
    const unsigned short* xrow = xb + (size_t)(m0 + l) * 256;
    #pragma unroll
    for (int kc = 0; kc < 8; ++kc) {
        const bf16x8 a = *reinterpret_cast<const bf16x8*>(xrow + kc * 32 + g * 8);
        #pragma unroll
        for (int j = 0; j < 4; ++j) {
            const bf16x8 b = *reinterpret_cast<const bf16x8*>(
                wz + (size_t)(nb + 16 * j + l) * 256 + kc * 32 + g * 8);
            acc[j] = __builtin_amdgcn_mfma_f32_16x16x32_bf16(a, b, acc[j], 0, 0, 0);
        }
    }

    int tok[4], bidx[4], hw[4];
    #pragma unroll
    for (int r = 0; r < 4; ++r) {
        tok[r]  = m0 + 4 * g + r;
        bidx[r] = tok[r] / kHW;
        hw[r]   = tok[r] - bidx[r] * kHW;
    }
    const float scl = (z == 1) ? kScale : 1.0f;

    if (z == 2) {
        #pragma unroll
        for (int j = 0; j < 4; ++j) {
            const int c = nb + 16 * j + l;
            const int head = c >> 5, d = c & 31;
            const float bias = bt[c];
            float t[4];
            #pragma unroll
            for (int r = 0; r < 4; ++r) t[r] = acc[j][r] + bias;
            #pragma unroll
            for (int r = 0; r < 4; ++r)
                vb[(((size_t)(bidx[r] * kHeads + head) * kHW + hw[r]) << 5) + d] = t[r];
            alignas(8) unsigned short u[4] = {f2bf_bits(t[0]), f2bf_bits(t[1]),
                                              f2bf_bits(t[2]), f2bf_bits(t[3])};
            *reinterpret_cast<unsigned long long*>(
                vt + ((size_t)(bidx[0] * kHeads + head) * kHD + d) * kHW + hw[0]) =
                *reinterpret_cast<unsigned long long*>(u);
        }
    } else {
        unsigned short* ob = (z == 0) ? qbh : kbh;
        #pragma unroll
        for (int j = 0; j < 4; ++j) {
            const int c = nb + 16 * j + l;
            const int head = c >> 5, d = c & 31;
            const float bias = bt[c];
            float t[4];
            #pragma unroll
            for (int r = 0; r < 4; ++r) t[r] = (acc[j][r] + bias) * scl;
            #pragma unroll
            for (int r = 0; r < 4; ++r) {
                const float p = __shfl_xor(t[r], 1);
                const float cs = cosb[hw[r] * 32 + d];
                const float sn = sinb[hw[r] * 32 + d];
                const float o = (d & 1) ? (t[r] * cs + p * sn)
                                        : (t[r] * cs - p * sn);
                ob[(((size_t)(bidx[r] * kHeads + head) * kHW + hw[r]) << 5) + d] =
                    f2bf_bits(o);
            }
        }
    }
}

// ---------------------------------------------------------------------------
// Kernel 3: LePE 5x5 depthwise conv on v (head-major in, token-major out)
// ---------------------------------------------------------------------------
__global__ __launch_bounds__(256) void lepe_kernel(
    const float* __restrict__ vb,
    const float* __restrict__ lw, const float* __restrict__ lb,
    float* __restrict__ lepe)
{
    const int c   = threadIdx.x;
    const int bhw = blockIdx.x;
    const int b   = bhw / kHW;
    const int hw  = bhw % kHW;
    const int h   = hw / kW;
    const int w   = hw % kW;
    const int head = c >> 5;
    const int d    = c & 31;

    const float* vsrc = vb + ((size_t)(b * kHeads + head) * kHW) * kHD + d;
    float acc = lb[c];
    #pragma unroll
    for (int dh = 0; dh < 5; ++dh) {
        const int h2 = h + dh - 2;
        if (h2 < 0 || h2 >= kH) continue;
        #pragma unroll
        for (int dw = 0; dw < 5; ++dw) {
            const int w2 = w + dw - 2;
            if (w2 < 0 || w2 >= kW) continue;
            acc += vsrc[(size_t)(h2 * kW + w2) * kHD] * lw[(dh * 5 + dw) * kC + c];
        }
    }
    lepe[(size_t)bhw * kC + c] = acc;
}

// ---------------------------------------------------------------------------
// Kernel 4: MFMA attention — R10 structure (KVBLK=64, 80KB LDS, 2 blocks/CU)
// + s_setprio around the MFMA/softmax core. 512 threads = 8 waves:
// wave w = (batch b=w&3, q-sub-tile sh=w>>2). Staging: every wave 1 mask gll;
// sh=0 waves 4 K glls, sh=1 waves 4 V glls -> 5 glls/wave, vmcnt(5).
// Pure-VALU P redistribution (permlane swaps). k-split partials (ks=2).
// ---------------------------------------------------------------------------
__global__ __launch_bounds__(512, 4) void attn_mfma_kernel(
    const __hip_bfloat16* __restrict__ qb, const __hip_bfloat16* __restrict__ kb,
    const __hip_bfloat16* __restrict__ vt, const float* __restrict__ mask,
    float* __restrict__ po, float* __restrict__ ls, int kspan)
{
    extern __shared__ __align__(16) char smem[];   // 2 x (8K mask + 16K K + 16K V)
    constexpr int kBufStride = 40960;
    constexpr int kKOff = 8192;
    constexpr int kVOff = 24576;

    const int head = blockIdx.y;
    const int ksl  = blockIdx.z;
    const int tid  = threadIdx.x;
    const int w    = tid >> 6;          // 0..7
    const int b    = w & 3;             // batch
    const int sh   = w >> 2;            // this wave's q-sub-tile (0 or 1)
    const int bh   = b * kHeads + head;
    const int lane = tid & 63;
    const int lq   = lane & 15;
    const int g    = lane >> 4;
    const int q0   = blockIdx.x * 32;
    const int kt0  = ksl * kspan;
    const int nt   = kspan >> 6;
    const bool odd16 = (g & 1);

    // Q B-fragment for this wave's sub-tile
    const bf16x8 qfrag = *reinterpret_cast<const bf16x8*>(
        reinterpret_cast<const unsigned short*>(qb) +
        ((size_t)bh * kHW + q0 + 16 * sh + lq) * kHD + g * 8);

    // staging sources (pre-swizzled; LDS written linearly)
    const float* msrc;
    {
        const int mrow = w * 4 + (lane >> 4);
        const int mcb  = (lane & 15) ^ (mrow & 7);
        msrc = mask + ((size_t)head * kHW + q0 + mrow) * kHW + kt0 + mcb * 4;
    }
    const unsigned short* kvsrc[4];
    int kvstep, kvregion;
    {
        const unsigned short* kb_bh =
            reinterpret_cast<const unsigned short*>(kb) + (size_t)bh * kHW * kHD;
        const unsigned short* vt_bh =
            reinterpret_cast<const unsigned short*>(vt) + (size_t)bh * kHD * kHW;
        if (sh == 0) {   // waves 0..3 stage K for their batch
            #pragma unroll
            for (int i = 0; i < 4; ++i) {
                const int key   = i * 16 + (lane >> 2);
                const int kslot = (lane & 3) ^ (key & 3);
                kvsrc[i] = kb_bh + (size_t)(kt0 + key) * kHD + kslot * 8;
            }
            kvstep = 64 * kHD;
            kvregion = kKOff;
        } else {         // waves 4..7 stage V
            #pragma unroll
            for (int i = 0; i < 4; ++i) {
                const int d   = i * 8 + (lane >> 3);
                const int vcu = (lane & 7) ^ (d & 7);
                kvsrc[i] = vt_bh + (size_t)d * kHW + kt0 + vcu * 8;
            }
            kvstep = 64;
            kvregion = kVOff;
        }
    }

    auto STAGE = [&](int bufo, int tt) {
        gll16(msrc + (size_t)tt * 64, smem + bufo + w * 1024);
        char* kv = smem + bufo + kvregion + b * 4096;
        #pragma unroll
        for (int i = 0; i < 4; ++i)
            gll16(kvsrc[i] + (size_t)tt * kvstep, kv + i * 1024);
    };

    f32x4 o0 = {0.f, 0.f, 0.f, 0.f};
    f32x4 o1 = {0.f, 0.f, 0.f, 0.f};
    float lsum = 0.f;

    // swizzled fragment read offsets
    const int koff = lq * 64 + ((g ^ (lq & 3)) * 16);
    const int vxa  = (g ^ (lq & 7)) * 16;
    const int vxb  = ((4 + g) ^ (lq & 7)) * 16;

    STAGE(0, 0);

    int cur = 0;
    for (int t = 0; t < nt; ++t) {
        if (t + 1 < nt) {
            STAGE(cur ^ kBufStride, t + 1);
            asm volatile("s_waitcnt vmcnt(5)" ::: "memory");
        } else {
            asm volatile("s_waitcnt vmcnt(0)" ::: "memory");
        }
        __builtin_amdgcn_s_barrier();
        __builtin_amdgcn_sched_barrier(0);

        const char* mb  = smem + cur;
        const char* kbf = smem + cur + kKOff + b * 4096;
        const char* vbf = smem + cur + kVOff + b * 4096;

        bf16x8 kf[4];
        #pragma unroll
        for (int j = 0; j < 4; ++j)
            kf[j] = *reinterpret_cast<const bf16x8*>(kbf + j * 1024 + koff);
        const bf16x8 va  = *reinterpret_cast<const bf16x8*>(vbf + lq * 128 + vxa);
        const bf16x8 vb2 = *reinterpret_cast<const bf16x8*>(vbf + lq * 128 + vxb);
        const bf16x8 vc  = *reinterpret_cast<const bf16x8*>(vbf + (16 + lq) * 128 + vxa);
        const bf16x8 vd  = *reinterpret_cast<const bf16x8*>(vbf + (16 + lq) * 128 + vxb);

        __builtin_amdgcn_s_setprio(1);
        f32x4 st[4];
        #pragma unroll
        for (int j = 0; j < 4; ++j) {
            const f32x4 mc = *reinterpret_cast<const f32x4*>(
                mb + sh * 4096 + lq * 256 + (((4 * j + g) ^ (lq & 7)) * 16));
            st[j] = __builtin_amdgcn_mfma_f32_16x16x32_bf16(kf[j], qfrag, mc, 0, 0, 0);
        }

        unsigned p32[4][2];
        #pragma unroll
        for (int j = 0; j < 4; ++j) {
            const float e0 = __expf(st[j][0]);
            const float e1 = __expf(st[j][1]);
            const float e2 = __expf(st[j][2]);
            const float e3 = __expf(st[j][3]);
            lsum += (e0 + e1) + (e2 + e3);
            p32[j][0] = cvt_pk_bf16(e0, e1);
            p32[j][1] = cvt_pk_bf16(e2, e3);
        }

        // P redistribution (S^T lane layout -> PV A-fragment), pure VALU
        unsigned sj[4][2][2];
        #pragma unroll
        for (int j = 0; j < 4; ++j)
            #pragma unroll
            for (int r = 0; r < 2; ++r) {
                unsigned a = p32[j][r], b2 = p32[j][r];
                permlane16_swap(a, b2);
                sj[j][r][0] = a; sj[j][r][1] = b2;
            }
        unsigned pw0[4], pw1[4];
        #pragma unroll
        for (int w2 = 0; w2 < 4; ++w2) {
            const int r = w2 & 1, c = w2 >> 1;
            unsigned pa = sj[0][r][c], pb = sj[1][r][c];
            permlane32_swap(pa, pb);
            pw0[w2] = odd16 ? pb : pa;
            unsigned qa = sj[2][r][c], qb2 = sj[3][r][c];
            permlane32_swap(qa, qb2);
            pw1[w2] = odd16 ? qb2 : qa;
        }
        uint32x4 w0v = {pw0[0], pw0[1], pw0[2], pw0[3]};
        uint32x4 w1v = {pw1[0], pw1[1], pw1[2], pw1[3]};
        const bf16x8 pa0 = __builtin_bit_cast(bf16x8, w0v);
        const bf16x8 pa1 = __builtin_bit_cast(bf16x8, w1v);

        o0 = __builtin_amdgcn_mfma_f32_16x16x32_bf16(pa0, va,  o0, 0, 0, 0);
        o0 = __builtin_amdgcn_mfma_f32_16x16x32_bf16(pa1, vb2, o0, 0, 0, 0);
        o1 = __builtin_amdgcn_mfma_f32_16x16x32_bf16(pa0, vc,  o1, 0, 0, 0);
        o1 = __builtin_amdgcn_mfma_f32_16x16x32_bf16(pa1, vd,  o1, 0, 0, 0);
        __builtin_amdgcn_s_setprio(0);

        asm volatile("s_waitcnt lgkmcnt(0)" ::: "memory");
        __builtin_amdgcn_s_barrier();
        cur ^= kBufStride;
    }

    // row-sum (partial over this k-range) + un-normalized partial writes
    lsum += __shfl_xor(lsum, 16);
    lsum += __shfl_xor(lsum, 32);

    const size_t pbase = ((size_t)ksl * (kB * kHeads) + bh) * kHW;
    #pragma unroll
    for (int r = 0; r < 4; ++r) {
        float* orow = po + (pbase + q0 + 16 * sh + 4 * g + r) * kHD + lq;
        orow[0]  = o0[r];
        orow[16] = o1[r];
    }
    if (lane < 16) ls[pbase + q0 + 16 * sh + lq] = lsum;
}

// ---------------------------------------------------------------------------
// Kernel 5: output projection via bf16 MFMA, with fused combine:
// A[token][c] = (sum_s po[s]) / (sum_s ls[s]) + lepe, built in-register.
// grid (144 m-tiles of 64, 2 n-halves of 128), block 256 = 4 waves.
// ---------------------------------------------------------------------------
__global__ __launch_bounds__(256, 4) void out_mfma_kernel(
    const float* __restrict__ po, const float* __restrict__ ls,
    const float* __restrict__ lepe, const unsigned short* __restrict__ wt,
    const float* __restrict__ bo, float* __restrict__ out, int ks)
{
    const unsigned short* wz = wt + (size_t)3 * 65536;
    const int tid  = threadIdx.x;
    const int w    = tid >> 6;
    const int lane = tid & 63;
    const int l    = lane & 15;
    const int g    = lane >> 4;
    const int m0   = blockIdx.x * 64 + w * 16;
    const int nb   = blockIdx.y * 128;

    // A-row token for this lane
    const int tok = m0 + l;
    const int b   = tok / kHW;
    const int hw  = tok - b * kHW;
    const int bh0 = b * kHeads;

    // per-head inverse softmax denominators for this token
    float rinv[8];
    #pragma unroll
    for (int h = 0; h < 8; ++h) {
        float s = ls[((size_t)0 * 32 + bh0 + h) * kHW + hw];
        if (ks > 1) s += ls[((size_t)1 * 32 + bh0 + h) * kHW + hw];
        rinv[h] = 1.0f / s;
    }

    f32x4 acc[8] = {};
    #pragma unroll
    for (int kc = 0; kc < 8; ++kc) {
        // build A fragment: channels kc*32 + g*8 .. +7  (head = kc, d = g*8..)
        const float* p0 = po + (((size_t)0 * 32 + bh0 + kc) * kHW + hw) * kHD + g * 8;
        f32x4 sA = *reinterpret_cast<const f32x4*>(p0);
        f32x4 sB = *reinterpret_cast<const f32x4*>(p0 + 4);
        if (ks > 1) {
            const float* p1 = po + (((size_t)1 * 32 + bh0 + kc) * kHW + hw) * kHD + g * 8;
            const f32x4 tA = *reinterpret_cast<const f32x4*>(p1);
            const f32x4 tB = *reinterpret_cast<const f32x4*>(p1 + 4);
            #pragma unroll
            for (int i = 0; i < 4; ++i) { sA[i] += tA[i]; sB[i] += tB[i]; }
        }
        const float* le = lepe + (size_t)tok * 256 + kc * 32 + g * 8;
        const f32x4 lA = *reinterpret_cast<const f32x4*>(le);
        const f32x4 lB = *reinterpret_cast<const f32x4*>(le + 4);
        const float ri = rinv[kc];
        float av[8];
        #pragma unroll
        for (int i = 0; i < 4; ++i) {
            av[i]     = sA[i] * ri + lA[i];
            av[i + 4] = sB[i] * ri + lB[i];
        }
        uint32x4 ap = {cvt_pk_bf16(av[0], av[1]), cvt_pk_bf16(av[2], av[3]),
                       cvt_pk_bf16(av[4], av[5]), cvt_pk_bf16(av[6], av[7])};
        const bf16x8 a = __builtin_bit_cast(bf16x8, ap);

        #pragma unroll
        for (int j = 0; j < 8; ++j) {
            const bf16x8 bfr = *reinterpret_cast<const bf16x8*>(
                wz + (size_t)(nb + 16 * j + l) * 256 + kc * 32 + g * 8);
            acc[j] = __builtin_amdgcn_mfma_f32_16x16x32_bf16(a, bfr, acc[j], 0, 0, 0);
        }
    }

    #pragma unroll
    for (int j = 0; j < 8; ++j) {
        const int c = nb + 16 * j + l;
        const float bias = bo[c];
        #pragma unroll
        for (int r = 0; r < 4; ++r)
            out[(size_t)(m0 + 4 * g + r) * 256 + c] = acc[j][r] + bias;
    }
}

// ---------------------------------------------------------------------------
extern "C" void kernel_launch(void* const* d_in, const int* in_sizes, int n_in,
                              void* d_out, int out_size, void* d_ws, size_t ws_size,
                              hipStream_t stream)
{
    const float* x    = (const float*)d_in[0];
    const float* sinb = (const float*)d_in[1];
    const float* cosb = (const float*)d_in[2];
    const float* mask = (const float*)d_in[3];
    const float* Wq   = (const float*)d_in[4];
    const float* bq   = (const float*)d_in[5];
    const float* Wk   = (const float*)d_in[6];
    const float* bk   = (const float*)d_in[7];
    const float* Wv   = (const float*)d_in[8];
    const float* bv   = (const float*)d_in[9];
    const float* lw   = (const float*)d_in[10];
    const float* lb   = (const float*)d_in[11];
    const float* Wo   = (const float*)d_in[12];
    const float* bo   = (const float*)d_in[13];
    float* out = (float*)d_out;

    const size_t NT = (size_t)kB * kHeads * kHW * kHD;  // 2359296 per tensor
    // fixed: vb, lepe (f32) + xb, qbh, kbh, vt (bf16) + wt (512KB)
    const size_t fixed = NT * 4 * 2 + NT * 2 * 4 + 4 * 65536 * 2;

    int ks = 2;
    while (ks > 1) {
        const size_t need = fixed + (size_t)ks * (NT * 4 + (size_t)kB * kHeads * kHW * 4);
        if (need <= ws_size) break;
        ks >>= 1;
    }
    const int kspan = kHW / ks;

    char* base = (char*)d_ws;
    float* vb   = (float*)base;                      base += NT * 4;
    float* lepe = (float*)base;                      base += NT * 4;
    unsigned short* xb  = (unsigned short*)base;     base += NT * 2;
    unsigned short* qbh = (unsigned short*)base;     base += NT * 2;
    unsigned short* kbh = (unsigned short*)base;     base += NT * 2;
    unsigned short* vt  = (unsigned short*)base;     base += NT * 2;
    unsigned short* wt  = (unsigned short*)base;     base += (size_t)4 * 65536 * 2;
    float* po = (float*)base;                        base += (size_t)ks * NT * 4;
    float* ls = (float*)base;                        base += (size_t)ks * kB * kHeads * kHW * 4;

    prep_kernel<<<dim3(3328), 256, 0, stream>>>(x, Wq, Wk, Wv, Wo, xb, wt);
    qkv_mfma_kernel<<<dim3(144, 4, 3), 256, 0, stream>>>(
        xb, wt, bq, bk, bv, sinb, cosb, qbh, kbh, vt, vb);
    lepe_kernel<<<dim3(9216), 256, 0, stream>>>(vb, lw, lb, lepe);
    attn_mfma_kernel<<<dim3(72, 8, ks), 512, 81920, stream>>>(
        (const __hip_bfloat16*)qbh, (const __hip_bfloat16*)kbh,
        (const __hip_bfloat16*)vt, mask, po, ls, kspan);
    out_mfma_kernel<<<dim3(144, 2), 256, 0, stream>>>(
        po, ls, lepe, wt, bo, out, ks);
}

// Round 13
// 185.093 us; speedup vs baseline: 1.0296x; 1.0275x over previous
//
#include <hip/hip_runtime.h>
#include <hip/hip_bf16.h>
#include <math.h>

// Problem constants
constexpr int kB     = 4;
constexpr int kH     = 48;
constexpr int kW     = 48;
constexpr int kHW    = 2304;   // 48*48
constexpr int kC     = 256;
constexpr int kHeads = 8;
constexpr int kHD    = 32;
constexpr float kScale = 0.17677669529663687f;  // 32^-0.5

typedef __bf16 bf16x8 __attribute__((ext_vector_type(8)));
typedef float  f32x4  __attribute__((ext_vector_type(4)));
typedef unsigned int   uint32x4 __attribute__((ext_vector_type(4)));
typedef unsigned short ushort8v __attribute__((ext_vector_type(8)));

static __device__ __forceinline__ unsigned short f2bf_bits(float f) {
    return __builtin_bit_cast(unsigned short, __float2bfloat16(f));
}

// packed f32x2 -> bf16x2 (TRUNCATING — safe for P in (0,1], NOT for A matrix)
static __device__ __forceinline__ unsigned cvt_pk_bf16(float lo, float hi) {
    unsigned r;
    asm("v_cvt_pk_bf16_f32 %0, %1, %2" : "=v"(r) : "v"(lo), "v"(hi));
    return r;
}

// VALU cross-lane swaps (gfx950)
static __device__ __forceinline__ void permlane16_swap(unsigned& a, unsigned& b) {
    asm("v_permlane16_swap_b32 %0, %1" : "+v"(a), "+v"(b));
}
static __device__ __forceinline__ void permlane32_swap(unsigned& a, unsigned& b) {
    asm("v_permlane32_swap_b32 %0, %1" : "+v"(a), "+v"(b));
}

// async global->LDS, 16B per lane; LDS dest = wave-uniform base + lane*16
static __device__ __forceinline__ void gll16(const void* g, void* l) {
    __builtin_amdgcn_global_load_lds(
        (const __attribute__((address_space(1))) void*)g,
        (__attribute__((address_space(3))) void*)l, 16, 0, 0);
}

// ---------------------------------------------------------------------------
// Kernel 0: prep — cast x to bf16 + transpose Wq/Wk/Wv/Wo to bf16 Wt[n][k].
// ---------------------------------------------------------------------------
__global__ __launch_bounds__(256) void prep_kernel(
    const float* __restrict__ x,
    const float* __restrict__ Wq, const float* __restrict__ Wk,
    const float* __restrict__ Wv, const float* __restrict__ Wo,
    unsigned short* __restrict__ xb, unsigned short* __restrict__ wt)
{
    const int bid = blockIdx.x;
    if (bid < 2304) {
        const int i = (bid * 256 + threadIdx.x) * 4;
        const float4 v = *reinterpret_cast<const float4*>(x + i);
        alignas(8) unsigned short u[4] = {f2bf_bits(v.x), f2bf_bits(v.y),
                                          f2bf_bits(v.z), f2bf_bits(v.w)};
        *reinterpret_cast<unsigned long long*>(xb + i) =
            *reinterpret_cast<unsigned long long*>(u);
    } else {
        const int e = (bid - 2304) * 256 + threadIdx.x;
        const int m = e >> 16;
        const int r = e & 65535;
        const int k = r >> 8;
        const int n = r & 255;
        const float* W = (m == 0) ? Wq : ((m == 1) ? Wk : ((m == 2) ? Wv : Wo));
        wt[(size_t)m * 65536 + n * 256 + k] = f2bf_bits(W[k * 256 + n]);
    }
}

// ---------------------------------------------------------------------------
// Kernel 1: QKV projection via bf16 MFMA (fused bias/scale/RoPE; z=2 emits
// vt bf16 [bh][d][hw] + vb fp32).
// ---------------------------------------------------------------------------
__global__ __launch_bounds__(256) void qkv_mfma_kernel(
    const unsigned short* __restrict__ xb, const unsigned short* __restrict__ wt,
    const float* __restrict__ bq, const float* __restrict__ bk,
    const float* __restrict__ bv,
    const float* __restrict__ sinb, const float* __restrict__ cosb,
    unsigned short* __restrict__ qbh, unsigned short* __restrict__ kbh,
    unsigned short* __restrict__ vt, float* __restrict__ vb)
{
    const int z = blockIdx.z;
    const unsigned short* wz = wt + (size_t)z * 65536;
    const float* bt = (z == 0) ? bq : ((z == 1) ? bk : bv);
    const int tid  = threadIdx.x;
    const int w    = tid >> 6;
    const int lane = tid & 63;
    const int l    = lane & 15;
    const int g    = lane >> 4;
    const int m0   = blockIdx.x * 64 + w * 16;
    const int nb   = blockIdx.y * 64;

    f32x4 acc[4] = {};
    const unsigned short* xrow = xb + (size_t)(m0 + l) * 256;
    #pragma unroll
    for (int kc = 0; kc < 8; ++kc) {
        const bf16x8 a = *reinterpret_cast<const bf16x8*>(xrow + kc * 32 + g * 8);
        #pragma unroll
        for (int j = 0; j < 4; ++j) {
            const bf16x8 b = *reinterpret_cast<const bf16x8*>(
                wz + (size_t)(nb + 16 * j + l) * 256 + kc * 32 + g * 8);
            acc[j] = __builtin_amdgcn_mfma_f32_16x16x32_bf16(a, b, acc[j], 0, 0, 0);
        }
    }

    int tok[4], bidx[4], hw[4];
    #pragma unroll
    for (int r = 0; r < 4; ++r) {
        tok[r]  = m0 + 4 * g + r;
        bidx[r] = tok[r] / kHW;
        hw[r]   = tok[r] - bidx[r] * kHW;
    }
    const float scl = (z == 1) ? kScale : 1.0f;

    if (z == 2) {
        #pragma unroll
        for (int j = 0; j < 4; ++j) {
            const int c = nb + 16 * j + l;
            const int head = c >> 5, d = c & 31;
            const float bias = bt[c];
            float t[4];
            #pragma unroll
            for (int r = 0; r < 4; ++r) t[r] = acc[j][r] + bias;
            #pragma unroll
            for (int r = 0; r < 4; ++r)
                vb[(((size_t)(bidx[r] * kHeads + head) * kHW + hw[r]) << 5) + d] = t[r];
            alignas(8) unsigned short u[4] = {f2bf_bits(t[0]), f2bf_bits(t[1]),
                                              f2bf_bits(t[2]), f2bf_bits(t[3])};
            *reinterpret_cast<unsigned long long*>(
                vt + ((size_t)(bidx[0] * kHeads + head) * kHD + d) * kHW + hw[0]) =
                *reinterpret_cast<unsigned long long*>(u);
        }
    } else {
        unsigned short* ob = (z == 0) ? qbh : kbh;
        #pragma unroll
        for (int j = 0; j < 4; ++j) {
            const int c = nb + 16 * j + l;
            const int head = c >> 5, d = c & 31;
            const float bias = bt[c];
            float t[4];
            #pragma unroll
            for (int r = 0; r < 4; ++r) t[r] = (acc[j][r] + bias) * scl;
            #pragma unroll
            for (int r = 0; r < 4; ++r) {
                const float p = __shfl_xor(t[r], 1);
                const float cs = cosb[hw[r] * 32 + d];
                const float sn = sinb[hw[r] * 32 + d];
                const float o = (d & 1) ? (t[r] * cs + p * sn)
                                        : (t[r] * cs - p * sn);
                ob[(((size_t)(bidx[r] * kHeads + head) * kHW + hw[r]) << 5) + d] =
                    f2bf_bits(o);
            }
        }
    }
}

// ---------------------------------------------------------------------------
// Kernel 3: LePE 5x5 depthwise conv on v (head-major in, token-major out)
// ---------------------------------------------------------------------------
__global__ __launch_bounds__(256) void lepe_kernel(
    const float* __restrict__ vb,
    const float* __restrict__ lw, const float* __restrict__ lb,
    float* __restrict__ lepe)
{
    const int c   = threadIdx.x;
    const int bhw = blockIdx.x;
    const int b   = bhw / kHW;
    const int hw  = bhw % kHW;
    const int h   = hw / kW;
    const int w   = hw % kW;
    const int head = c >> 5;
    const int d    = c & 31;

    const float* vsrc = vb + ((size_t)(b * kHeads + head) * kHW) * kHD + d;
    float acc = lb[c];
    #pragma unroll
    for (int dh = 0; dh < 5; ++dh) {
        const int h2 = h + dh - 2;
        if (h2 < 0 || h2 >= kH) continue;
        #pragma unroll
        for (int dw = 0; dw < 5; ++dw) {
            const int w2 = w + dw - 2;
            if (w2 < 0 || w2 >= kW) continue;
            acc += vsrc[(size_t)(h2 * kW + w2) * kHD] * lw[(dh * 5 + dw) * kC + c];
        }
    }
    lepe[(size_t)bhw * kC + c] = acc;
}

// ---------------------------------------------------------------------------
// Kernel 4: MFMA attention — R10 structure (KVBLK=64, 80KB LDS, 2 blocks/CU)
// + s_setprio around the MFMA/softmax core. 512 threads = 8 waves:
// wave w = (batch b=w&3, q-sub-tile sh=w>>2). Staging: every wave 1 mask gll;
// sh=0 waves 4 K glls, sh=1 waves 4 V glls -> 5 glls/wave, vmcnt(5).
// Pure-VALU P redistribution (permlane swaps). k-split partials (ks=2).
// ---------------------------------------------------------------------------
__global__ __launch_bounds__(512, 4) void attn_mfma_kernel(
    const __hip_bfloat16* __restrict__ qb, const __hip_bfloat16* __restrict__ kb,
    const __hip_bfloat16* __restrict__ vt, const float* __restrict__ mask,
    float* __restrict__ po, float* __restrict__ ls, int kspan)
{
    extern __shared__ __align__(16) char smem[];   // 2 x (8K mask + 16K K + 16K V)
    constexpr int kBufStride = 40960;
    constexpr int kKOff = 8192;
    constexpr int kVOff = 24576;

    const int head = blockIdx.y;
    const int ksl  = blockIdx.z;
    const int tid  = threadIdx.x;
    const int w    = tid >> 6;          // 0..7
    const int b    = w & 3;             // batch
    const int sh   = w >> 2;            // this wave's q-sub-tile (0 or 1)
    const int bh   = b * kHeads + head;
    const int lane = tid & 63;
    const int lq   = lane & 15;
    const int g    = lane >> 4;
    const int q0   = blockIdx.x * 32;
    const int kt0  = ksl * kspan;
    const int nt   = kspan >> 6;
    const bool odd16 = (g & 1);

    // Q B-fragment for this wave's sub-tile
    const bf16x8 qfrag = *reinterpret_cast<const bf16x8*>(
        reinterpret_cast<const unsigned short*>(qb) +
        ((size_t)bh * kHW + q0 + 16 * sh + lq) * kHD + g * 8);

    // staging sources (pre-swizzled; LDS written linearly)
    const float* msrc;
    {
        const int mrow = w * 4 + (lane >> 4);
        const int mcb  = (lane & 15) ^ (mrow & 7);
        msrc = mask + ((size_t)head * kHW + q0 + mrow) * kHW + kt0 + mcb * 4;
    }
    const unsigned short* kvsrc[4];
    int kvstep, kvregion;
    {
        const unsigned short* kb_bh =
            reinterpret_cast<const unsigned short*>(kb) + (size_t)bh * kHW * kHD;
        const unsigned short* vt_bh =
            reinterpret_cast<const unsigned short*>(vt) + (size_t)bh * kHD * kHW;
        if (sh == 0) {   // waves 0..3 stage K for their batch
            #pragma unroll
            for (int i = 0; i < 4; ++i) {
                const int key   = i * 16 + (lane >> 2);
                const int kslot = (lane & 3) ^ (key & 3);
                kvsrc[i] = kb_bh + (size_t)(kt0 + key) * kHD + kslot * 8;
            }
            kvstep = 64 * kHD;
            kvregion = kKOff;
        } else {         // waves 4..7 stage V
            #pragma unroll
            for (int i = 0; i < 4; ++i) {
                const int d   = i * 8 + (lane >> 3);
                const int vcu = (lane & 7) ^ (d & 7);
                kvsrc[i] = vt_bh + (size_t)d * kHW + kt0 + vcu * 8;
            }
            kvstep = 64;
            kvregion = kVOff;
        }
    }

    auto STAGE = [&](int bufo, int tt) {
        gll16(msrc + (size_t)tt * 64, smem + bufo + w * 1024);
        char* kv = smem + bufo + kvregion + b * 4096;
        #pragma unroll
        for (int i = 0; i < 4; ++i)
            gll16(kvsrc[i] + (size_t)tt * kvstep, kv + i * 1024);
    };

    f32x4 o0 = {0.f, 0.f, 0.f, 0.f};
    f32x4 o1 = {0.f, 0.f, 0.f, 0.f};
    float lsum = 0.f;

    // swizzled fragment read offsets
    const int koff = lq * 64 + ((g ^ (lq & 3)) * 16);
    const int vxa  = (g ^ (lq & 7)) * 16;
    const int vxb  = ((4 + g) ^ (lq & 7)) * 16;

    STAGE(0, 0);

    int cur = 0;
    for (int t = 0; t < nt; ++t) {
        if (t + 1 < nt) {
            STAGE(cur ^ kBufStride, t + 1);
            asm volatile("s_waitcnt vmcnt(5)" ::: "memory");
        } else {
            asm volatile("s_waitcnt vmcnt(0)" ::: "memory");
        }
        __builtin_amdgcn_s_barrier();
        __builtin_amdgcn_sched_barrier(0);

        const char* mb  = smem + cur;
        const char* kbf = smem + cur + kKOff + b * 4096;
        const char* vbf = smem + cur + kVOff + b * 4096;

        bf16x8 kf[4];
        #pragma unroll
        for (int j = 0; j < 4; ++j)
            kf[j] = *reinterpret_cast<const bf16x8*>(kbf + j * 1024 + koff);
        const bf16x8 va  = *reinterpret_cast<const bf16x8*>(vbf + lq * 128 + vxa);
        const bf16x8 vb2 = *reinterpret_cast<const bf16x8*>(vbf + lq * 128 + vxb);
        const bf16x8 vc  = *reinterpret_cast<const bf16x8*>(vbf + (16 + lq) * 128 + vxa);
        const bf16x8 vd  = *reinterpret_cast<const bf16x8*>(vbf + (16 + lq) * 128 + vxb);

        __builtin_amdgcn_s_setprio(1);
        f32x4 st[4];
        #pragma unroll
        for (int j = 0; j < 4; ++j) {
            const f32x4 mc = *reinterpret_cast<const f32x4*>(
                mb + sh * 4096 + lq * 256 + (((4 * j + g) ^ (lq & 7)) * 16));
            st[j] = __builtin_amdgcn_mfma_f32_16x16x32_bf16(kf[j], qfrag, mc, 0, 0, 0);
        }

        unsigned p32[4][2];
        #pragma unroll
        for (int j = 0; j < 4; ++j) {
            const float e0 = __expf(st[j][0]);
            const float e1 = __expf(st[j][1]);
            const float e2 = __expf(st[j][2]);
            const float e3 = __expf(st[j][3]);
            lsum += (e0 + e1) + (e2 + e3);
            p32[j][0] = cvt_pk_bf16(e0, e1);
            p32[j][1] = cvt_pk_bf16(e2, e3);
        }

        // P redistribution (S^T lane layout -> PV A-fragment), pure VALU
        unsigned sj[4][2][2];
        #pragma unroll
        for (int j = 0; j < 4; ++j)
            #pragma unroll
            for (int r = 0; r < 2; ++r) {
                unsigned a = p32[j][r], b2 = p32[j][r];
                permlane16_swap(a, b2);
                sj[j][r][0] = a; sj[j][r][1] = b2;
            }
        unsigned pw0[4], pw1[4];
        #pragma unroll
        for (int w2 = 0; w2 < 4; ++w2) {
            const int r = w2 & 1, c = w2 >> 1;
            unsigned pa = sj[0][r][c], pb = sj[1][r][c];
            permlane32_swap(pa, pb);
            pw0[w2] = odd16 ? pb : pa;
            unsigned qa = sj[2][r][c], qb2 = sj[3][r][c];
            permlane32_swap(qa, qb2);
            pw1[w2] = odd16 ? qb2 : qa;
        }
        uint32x4 w0v = {pw0[0], pw0[1], pw0[2], pw0[3]};
        uint32x4 w1v = {pw1[0], pw1[1], pw1[2], pw1[3]};
        const bf16x8 pa0 = __builtin_bit_cast(bf16x8, w0v);
        const bf16x8 pa1 = __builtin_bit_cast(bf16x8, w1v);

        o0 = __builtin_amdgcn_mfma_f32_16x16x32_bf16(pa0, va,  o0, 0, 0, 0);
        o0 = __builtin_amdgcn_mfma_f32_16x16x32_bf16(pa1, vb2, o0, 0, 0, 0);
        o1 = __builtin_amdgcn_mfma_f32_16x16x32_bf16(pa0, vc,  o1, 0, 0, 0);
        o1 = __builtin_amdgcn_mfma_f32_16x16x32_bf16(pa1, vd,  o1, 0, 0, 0);
        __builtin_amdgcn_s_setprio(0);

        asm volatile("s_waitcnt lgkmcnt(0)" ::: "memory");
        __builtin_amdgcn_s_barrier();
        cur ^= kBufStride;
    }

    // row-sum (partial over this k-range) + un-normalized partial writes
    lsum += __shfl_xor(lsum, 16);
    lsum += __shfl_xor(lsum, 32);

    const size_t pbase = ((size_t)ksl * (kB * kHeads) + bh) * kHW;
    #pragma unroll
    for (int r = 0; r < 4; ++r) {
        float* orow = po + (pbase + q0 + 16 * sh + 4 * g + r) * kHD + lq;
        orow[0]  = o0[r];
        orow[16] = o1[r];
    }
    if (lane < 16) ls[pbase + q0 + 16 * sh + lq] = lsum;
}

// ---------------------------------------------------------------------------
// Kernel 4b: combine k-split partials + lepe add -> bf16 A matrix for out proj
// (RNE conversion via __float2bfloat16 — numerics-critical, do NOT cvt_pk)
// ---------------------------------------------------------------------------
__global__ __launch_bounds__(256) void combine_kernel(
    const float* __restrict__ po, const float* __restrict__ ls,
    const float* __restrict__ lepe, unsigned short* __restrict__ abh, int ks)
{
    const int idx = blockIdx.x * 256 + threadIdx.x;
    const int c   = idx & 255;
    const int bhw = idx >> 8;
    const int b   = bhw / kHW;
    const int hw  = bhw % kHW;
    const int head = c >> 5;
    const int d    = c & 31;
    const int bh   = b * kHeads + head;

    float o = 0.f, l = 0.f;
    for (int s = 0; s < ks; ++s) {
        const size_t pbase = ((size_t)s * (kB * kHeads) + bh) * kHW + hw;
        o += po[pbase * kHD + d];
        l += ls[pbase];
    }
    abh[(size_t)idx] = f2bf_bits(o / l + lepe[idx]);
}

// ---------------------------------------------------------------------------
// Kernel 5: output projection via bf16 MFMA (dense bf16 A reads).
// ---------------------------------------------------------------------------
__global__ __launch_bounds__(256) void out_mfma_kernel(
    const unsigned short* __restrict__ abh, const unsigned short* __restrict__ wt,
    const float* __restrict__ bo, float* __restrict__ out)
{
    const unsigned short* wz = wt + (size_t)3 * 65536;
    const int tid  = threadIdx.x;
    const int w    = tid >> 6;
    const int lane = tid & 63;
    const int l    = lane & 15;
    const int g    = lane >> 4;
    const int m0   = blockIdx.x * 64 + w * 16;
    const int nb   = blockIdx.y * 64;

    f32x4 acc[4] = {};
    const unsigned short* arow = abh + (size_t)(m0 + l) * 256;
    #pragma unroll
    for (int kc = 0; kc < 8; ++kc) {
        const bf16x8 a = *reinterpret_cast<const bf16x8*>(arow + kc * 32 + g * 8);
        #pragma unroll
        for (int j = 0; j < 4; ++j) {
            const bf16x8 b = *reinterpret_cast<const bf16x8*>(
                wz + (size_t)(nb + 16 * j + l) * 256 + kc * 32 + g * 8);
            acc[j] = __builtin_amdgcn_mfma_f32_16x16x32_bf16(a, b, acc[j], 0, 0, 0);
        }
    }

    #pragma unroll
    for (int j = 0; j < 4; ++j) {
        const int c = nb + 16 * j + l;
        const float bias = bo[c];
        #pragma unroll
        for (int r = 0; r < 4; ++r)
            out[(size_t)(m0 + 4 * g + r) * 256 + c] = acc[j][r] + bias;
    }
}

// ---------------------------------------------------------------------------
extern "C" void kernel_launch(void* const* d_in, const int* in_sizes, int n_in,
                              void* d_out, int out_size, void* d_ws, size_t ws_size,
                              hipStream_t stream)
{
    const float* x    = (const float*)d_in[0];
    const float* sinb = (const float*)d_in[1];
    const float* cosb = (const float*)d_in[2];
    const float* mask = (const float*)d_in[3];
    const float* Wq   = (const float*)d_in[4];
    const float* bq   = (const float*)d_in[5];
    const float* Wk   = (const float*)d_in[6];
    const float* bk   = (const float*)d_in[7];
    const float* Wv   = (const float*)d_in[8];
    const float* bv   = (const float*)d_in[9];
    const float* lw   = (const float*)d_in[10];
    const float* lb   = (const float*)d_in[11];
    const float* Wo   = (const float*)d_in[12];
    const float* bo   = (const float*)d_in[13];
    float* out = (float*)d_out;

    const size_t NT = (size_t)kB * kHeads * kHW * kHD;  // 2359296 per tensor
    // fixed: vb, lepe (f32) + xb, abh, qbh, kbh, vt (bf16) + wt (512KB)
    const size_t fixed = NT * 4 * 2 + NT * 2 * 5 + 4 * 65536 * 2;

    int ks = 2;
    while (ks > 1) {
        const size_t need = fixed + (size_t)ks * (NT * 4 + (size_t)kB * kHeads * kHW * 4);
        if (need <= ws_size) break;
        ks >>= 1;
    }
    const int kspan = kHW / ks;

    char* base = (char*)d_ws;
    float* vb   = (float*)base;                      base += NT * 4;
    float* lepe = (float*)base;                      base += NT * 4;
    unsigned short* xb  = (unsigned short*)base;     base += NT * 2;
    unsigned short* abh = (unsigned short*)base;     base += NT * 2;
    unsigned short* qbh = (unsigned short*)base;     base += NT * 2;
    unsigned short* kbh = (unsigned short*)base;     base += NT * 2;
    unsigned short* vt  = (unsigned short*)base;     base += NT * 2;
    unsigned short* wt  = (unsigned short*)base;     base += (size_t)4 * 65536 * 2;
    float* po = (float*)base;                        base += (size_t)ks * NT * 4;
    float* ls = (float*)base;                        base += (size_t)ks * kB * kHeads * kHW * 4;

    prep_kernel<<<dim3(3328), 256, 0, stream>>>(x, Wq, Wk, Wv, Wo, xb, wt);
    qkv_mfma_kernel<<<dim3(144, 4, 3), 256, 0, stream>>>(
        xb, wt, bq, bk, bv, sinb, cosb, qbh, kbh, vt, vb);
    lepe_kernel<<<dim3(9216), 256, 0, stream>>>(vb, lw, lb, lepe);
    attn_mfma_kernel<<<dim3(72, 8, ks), 512, 81920, stream>>>(
        (const __hip_bfloat16*)qbh, (const __hip_bfloat16*)kbh,
        (const __hip_bfloat16*)vt, mask, po, ls, kspan);
    combine_kernel<<<dim3(9216), 256, 0, stream>>>(po, ls, lepe, abh, ks);
    out_mfma_kernel<<<dim3(144, 4), 256, 0, stream>>>(abh, wt, bo, out);
}